// Round 11
// baseline (159.697 us; speedup 1.0000x reference)
//
#include <hip/hip_runtime.h>
#include <math.h>

#define Bn 8
#define Hn 128
#define Ln 4096
#define LF 2049           // Ln/2 + 1
#define NROWS (Bn*Hn)     // 1024
#define NT 32             // frequency columns per mixmm block
#define NTILES 65         // ceil(2049/32) per batch
#define PLSZ 4096         // halfs per data plane (32 x 128)
#define WPLSZ 16384       // halfs per weight plane (128 x 128)
#define TSCALE 64.0f      // T stored as T/64 (fp16 range guard); W2 pre-scaled x64
#define ISCALE 64.0f      // irfft step-1 planes stored /64; GELU scale = 64/2048

// FFT LDS layouts
#define SKEW(a) ((a) + ((a) >> 4))                 // X buffer: stride-16 writes -> <=2-way
#define ZROW 2064                                   // 129*16 float2 per row (z stage)
#define XROW 2176                                   // SKEW(2047)+1 rounded (X buffer)
#define ZIDX(n) (129 * ((n) >> 7) + ((n) & 127))    // z[n1+128*n2] at 129*n2+n1 (conflict-dodge)

typedef _Float16 f16x8 __attribute__((ext_vector_type(8)));
typedef float f32x4 __attribute__((ext_vector_type(4)));

__device__ __forceinline__ void fsincos(float a, float* s, float* c) {
    *s = __sinf(a);
    *c = __cosf(a);
}
__device__ __forceinline__ float2 cm(float2 a, float2 b) {   // complex mult
    return make_float2(a.x * b.x - a.y * b.y, a.x * b.y + a.y * b.x);
}

template <int SIGN>
__device__ __forceinline__ void dft4(float2 a0, float2 a1, float2 a2, float2 a3,
                                     float2& y0, float2& y1, float2& y2, float2& y3) {
    float t0x = a0.x + a2.x, t0y = a0.y + a2.y;
    float t1x = a0.x - a2.x, t1y = a0.y - a2.y;
    float t2x = a1.x + a3.x, t2y = a1.y + a3.y;
    float t3x = a1.x - a3.x, t3y = a1.y - a3.y;
    y0 = make_float2(t0x + t2x, t0y + t2y);
    y2 = make_float2(t0x - t2x, t0y - t2y);
    y1 = make_float2(t1x - (float)SIGN * t3y, t1y + (float)SIGN * t3x);
    y3 = make_float2(t1x + (float)SIGN * t3y, t1y - (float)SIGN * t3x);
}

// ---------------------------------------------------------------------------
// prep: weight planes {r,i} fp16 for mixmm (W1,W2,W3), FFT twiddle table tw,
// and F128[m][k] = e^{-2pi i mk/128} fp16 planes for the four-step FFT GEMM.
//   blocks 0-63 W1 | 64-127 W2 | 128-143 W3 | 144-151 tw | 152-159 F128
// ---------------------------------------------------------------------------
__device__ __forceinline__ void write2(_Float16* __restrict__ W, int idx,
                                       float vr, float vi) {
    W[0 * WPLSZ + idx] = (_Float16)vr;
    W[1 * WPLSZ + idx] = (_Float16)vi;
}

__global__ __launch_bounds__(256) void prep_all_k(
        const float* __restrict__ B_ri, const float* __restrict__ C_ri,
        const float* __restrict__ D_ri,
        _Float16* __restrict__ W1, _Float16* __restrict__ W2,
        _Float16* __restrict__ W3, float2* __restrict__ tw,
        _Float16* __restrict__ F128) {
    __shared__ float2 roots[128];
    __shared__ float2 stage[2048];
    __shared__ float2 Gs[8 * 128];
    const int bid = blockIdx.x;
    const int tid = threadIdx.x;

    if (tid < 128) {
        float ang = 3.14159265358979f * (float)tid / 64.0f;
        float sw, cw; fsincos(ang, &sw, &cw);
        roots[tid] = make_float2(cw, sw);
    }
    __syncthreads();

    if (bid < 64) {
        const float2* B2f = (const float2*)B_ri;
        stage[tid] = B2f[bid * 256 + tid];
        __syncthreads();
        const int pl = tid >> 7, h = tid & 127;
        float sr = 0.f, si = 0.f;
        #pragma unroll 8
        for (int q = 0; q < 128; ++q) {
            float2 rt = roots[(q * h) & 127];
            float2 bv = stage[(pl << 7) + q];
            sr += bv.x * rt.x + bv.y * rt.y;
            si += bv.y * rt.x - bv.x * rt.y;
        }
        write2(W1, bid * 256 + tid, sr, si);
    } else if (bid < 128) {
        const int bid2 = bid - 64;
        const float2* C2f = (const float2*)C_ri;
        const int h = 2 * bid2 + (tid >> 7), p = tid & 127;
        float sr = 0.f, si = 0.f;
        for (int chunk = 0; chunk < 8; ++chunk) {
            __syncthreads();
            #pragma unroll
            for (int i = 0; i < 8; ++i) stage[tid + i * 256] = C2f[chunk * 2048 + tid + i * 256];
            __syncthreads();
            #pragma unroll
            for (int j = 0; j < 16; ++j) {
                int h2 = chunk * 16 + j;
                float2 cv = stage[j * 128 + p];
                float2 rt = roots[(h * h2) & 127];
                sr += cv.x * rt.x - cv.y * rt.y;
                si += cv.x * rt.y + cv.y * rt.x;
            }
        }
        write2(W2, bid2 * 256 + tid, sr * (TSCALE / 128.0f), si * (TSCALE / 128.0f));
    } else if (bid < 144) {
        const int h0 = (bid - 128) * 8;
        const int hh = tid >> 5, ci = tid & 31;
        const float2* D2f = (const float2*)D_ri;
        float2 g[4];
        #pragma unroll
        for (int cc = 0; cc < 4; ++cc) g[cc] = make_float2(0.f, 0.f);
        for (int chunk = 0; chunk < 8; ++chunk) {
            __syncthreads();
            #pragma unroll
            for (int i = 0; i < 8; ++i) stage[tid + i * 256] = D2f[chunk * 2048 + tid + i * 256];
            __syncthreads();
            #pragma unroll
            for (int j = 0; j < 16; ++j) {
                int a = chunk * 16 + j;
                float2 rt = roots[((h0 + hh) * a) & 127];
                #pragma unroll
                for (int cc = 0; cc < 4; ++cc) {
                    float2 dv = stage[j * 128 + ci + 32 * cc];
                    g[cc].x += dv.x * rt.x - dv.y * rt.y;
                    g[cc].y += dv.x * rt.y + dv.y * rt.x;
                }
            }
        }
        #pragma unroll
        for (int cc = 0; cc < 4; ++cc)
            Gs[hh * 128 + ci + 32 * cc] = make_float2(g[cc].x * (1.0f / 128.0f),
                                                      g[cc].y * (1.0f / 128.0f));
        __syncthreads();
        float2 wacc[4];
        #pragma unroll
        for (int qq = 0; qq < 4; ++qq) wacc[qq] = make_float2(0.f, 0.f);
        #pragma unroll 4
        for (int c = 0; c < 128; ++c) {
            float2 gv = Gs[hh * 128 + c];
            #pragma unroll
            for (int qq = 0; qq < 4; ++qq) {
                int q = ci + 32 * qq;
                float2 rt = roots[(c * q) & 127];
                wacc[qq].x += gv.x * rt.x + gv.y * rt.y;
                wacc[qq].y += gv.y * rt.x - gv.x * rt.y;
            }
        }
        #pragma unroll
        for (int qq = 0; qq < 4; ++qq)
            write2(W3, (h0 + hh) * 128 + ci + 32 * qq, wacc[qq].x, wacc[qq].y);
    } else if (bid < 152) {
        int m = (bid - 144) * 256 + tid;    // 0..2047
        float ang = -3.14159265358979f * (float)m / 1024.0f;
        float sw, cw;
        __sincosf(ang, &sw, &cw);
        tw[m] = make_float2(cw, sw);
    } else {
        // F128[m][k] = e^{-2pi i (m k)/128}
        #pragma unroll
        for (int j = 0; j < 8; ++j) {
            int e = (bid - 152) * 2048 + tid + j * 256;
            int m = e >> 7, k = e & 127;
            float ang = -3.14159265358979f * (float)((m * k) & 127) / 64.0f;
            float sw, cw; fsincos(ang, &sw, &cw);
            F128[e] = (_Float16)cw;
            F128[WPLSZ + e] = (_Float16)sw;
        }
    }
}

// ---------------------------------------------------------------------------
// Four-step 2048-pt FFT core (FORWARD only; inverse = conj-in, conj-out):
//   z[n1+128 n2] staged in zx at ZIDX; per thread (n1, row) DFT-16 along n2,
//   twiddle tw[n1*k2], store fp16 B-planes [n=row*16+k2][k=n1] (XOR swizzle);
//   then MFMA: X[k2+16 k1] = sum_n1 F128[k1][n1] * B[n1][k2]  (mixmm skeleton)
//   X stored fp32 in zx at row*XROW + SKEW(k2+16*k1).
// Precision: B fp16 (DFT-16 partials), F128 fp16 unit-magnitude — same class
// as mixmm's proven fp16 path. bscale guards fp16 range for irfft.
// ---------------------------------------------------------------------------
__device__ __forceinline__ f32x4 mfma16h(f16x8 a, f16x8 b, f32x4 c) {
    return __builtin_amdgcn_mfma_f32_16x16x32_f16(a, b, c, 0, 0, 0);
}
__device__ __forceinline__ f16x8 read_frag(const _Float16* plane, int n, int k) {
    int ksw = k ^ ((n & 7) << 3);
    return *(const f16x8*)(plane + n * 128 + ksw);
}
__device__ __forceinline__ f16x8 aread(const _Float16* W, int pl, int m, int k) {
    return *(const f16x8*)(W + pl * WPLSZ + m * 128 + k);
}

__device__ __forceinline__ void fourstep2048(float2* zx, _Float16* Bpl,
                                             const _Float16* __restrict__ F128,
                                             const float2* __restrict__ tw,
                                             int tid, float bscale) {
    // ---- steps 1-2: DFT-16 + twiddle, per thread (row=tid>>7, n1=tid&127) ----
    {
        const int rl = tid >> 7, n1 = tid & 127;
        float2 a[16];
        #pragma unroll
        for (int n2 = 0; n2 < 16; ++n2) a[n2] = zx[rl * ZROW + 129 * n2 + n1];
        // W16^k constants (forward, e^{-2pi i k/16})
        const float2 K1 = make_float2(0.92387953f, -0.38268343f);
        const float2 K2 = make_float2(0.70710678f, -0.70710678f);
        const float2 K3 = make_float2(0.38268343f, -0.92387953f);
        const float2 K4 = make_float2(0.f, -1.f);
        const float2 K6 = make_float2(-0.70710678f, -0.70710678f);
        const float2 K9 = make_float2(-0.92387953f, 0.38268343f);
        float2 b16[16], y0, y1, y2, y3;
        dft4<-1>(a[0], a[4], a[8], a[12], y0, y1, y2, y3);
        b16[0] = y0; b16[1] = y1; b16[2] = y2; b16[3] = y3;
        dft4<-1>(a[1], a[5], a[9], a[13], y0, y1, y2, y3);
        b16[4] = y0; b16[5] = cm(y1, K1); b16[6] = cm(y2, K2); b16[7] = cm(y3, K3);
        dft4<-1>(a[2], a[6], a[10], a[14], y0, y1, y2, y3);
        b16[8] = y0; b16[9] = cm(y1, K2); b16[10] = cm(y2, K4); b16[11] = cm(y3, K6);
        dft4<-1>(a[3], a[7], a[11], a[15], y0, y1, y2, y3);
        b16[12] = y0; b16[13] = cm(y1, K3); b16[14] = cm(y2, K6); b16[15] = cm(y3, K9);
        float2 X16[16];
        #pragma unroll
        for (int q = 0; q < 4; ++q) {
            dft4<-1>(b16[q], b16[q + 4], b16[q + 8], b16[q + 12], y0, y1, y2, y3);
            X16[q] = y0; X16[q + 4] = y1; X16[q + 8] = y2; X16[q + 12] = y3;
        }
        #pragma unroll
        for (int k2 = 0; k2 < 16; ++k2) {
            float2 v = X16[k2];
            if (k2) v = cm(v, tw[(n1 * k2) & 2047]);
            int n = rl * 16 + k2;
            int ksw = n1 ^ ((n & 7) << 3);
            Bpl[0 * PLSZ + n * 128 + ksw] = (_Float16)(v.x * bscale);
            Bpl[1 * PLSZ + n * 128 + ksw] = (_Float16)(v.y * bscale);
        }
    }
    __syncthreads();   // B-planes ready; all zx (z) reads complete

    // ---- step 3: MFMA  X = F128 @ B  (mixmm stage-1 skeleton) ----
    const int lane = tid & 63;
    const int w = tid >> 6;
    const int m15 = lane & 15;
    const int quad = lane >> 4;
    f32x4 accR[2][2], accM[2][2], accI[2][2];
    #pragma unroll
    for (int s = 0; s < 2; ++s)
        #pragma unroll
        for (int t = 0; t < 2; ++t) {
            accR[s][t] = (f32x4)0.f; accM[s][t] = (f32x4)0.f; accI[s][t] = (f32x4)0.f;
        }
    #pragma unroll
    for (int kb = 0; kb < 4; ++kb) {
        int k = kb * 32 + quad * 8;
        f16x8 wr[2], wi[2];
        #pragma unroll
        for (int s = 0; s < 2; ++s) {
            int m = w * 32 + s * 16 + m15;
            wr[s] = aread(F128, 0, m, k);
            wi[s] = aread(F128, 1, m, k);
        }
        f16x8 br[2], bi[2];
        #pragma unroll
        for (int t = 0; t < 2; ++t) {
            br[t] = read_frag(Bpl + 0 * PLSZ, t * 16 + m15, k);
            bi[t] = read_frag(Bpl + 1 * PLSZ, t * 16 + m15, k);
        }
        #pragma unroll
        for (int s = 0; s < 2; ++s)
            #pragma unroll
            for (int t = 0; t < 2; ++t) {
                accR[s][t] = mfma16h(wr[s], br[t], accR[s][t]);
                accM[s][t] = mfma16h(wi[s], bi[t], accM[s][t]);
                accI[s][t] = mfma16h(wr[s], bi[t], accI[s][t]);
                accI[s][t] = mfma16h(wi[s], br[t], accI[s][t]);
            }
    }
    // ---- X writes: row t, X[k2+16*k1], skewed ----
    #pragma unroll
    for (int s = 0; s < 2; ++s)
        #pragma unroll
        for (int t = 0; t < 2; ++t)
            #pragma unroll
            for (int reg = 0; reg < 4; ++reg) {
                int k1 = w * 32 + s * 16 + quad * 4 + reg;
                zx[t * XROW + SKEW(m15 + 16 * k1)] =
                    make_float2(accR[s][t][reg] - accM[s][t][reg], accI[s][t][reg]);
            }
    __syncthreads();   // X visible
}

// rfft: 2 rows/block; pack z = u[2n]+i u[2n+1]; four-step; Hermitian unpack.
__global__ __launch_bounds__(256, 3) void rfft_rows_k(const float* __restrict__ u,
                                                      float2* __restrict__ Uhat,
                                                      const float2* __restrict__ tw,
                                                      const _Float16* __restrict__ F128) {
    __shared__ __align__(16) float2 zx[2 * XROW];        // z stage / X buffer union
    __shared__ __align__(16) _Float16 Bpl[2 * PLSZ];
    const int tid = threadIdx.x;
    const int row0 = 2 * blockIdx.x;
    const float4* up4 = (const float4*)(u + (size_t)row0 * Ln);
    #pragma unroll
    for (int r = 0; r < 8; ++r) {
        int g = tid + (r << 8);              // 0..2047 float4s (2 rows)
        float4 v = up4[g];
        int rl = g >> 10, f = g & 1023;
        int n = 2 * f;
        int dst = rl * ZROW + 129 * (n >> 7) + (n & 127);
        zx[dst] = make_float2(v.x, v.y);
        zx[dst + 1] = make_float2(v.z, v.w);
    }
    __syncthreads();
    fourstep2048(zx, Bpl, F128, tw, tid, 1.0f);
    #pragma unroll
    for (int r = 0; r < 2; ++r) {
        float2* op = Uhat + (size_t)(row0 + r) * LF;
        const float2* X = zx + r * XROW;
        for (int l = tid; l < 1025; l += 256) {
            float2 Zl = X[SKEW(l)];
            float2 Zm = X[SKEW((2048 - l) & 2047)];
            float2 Fe = make_float2(0.5f * (Zl.x + Zm.x), 0.5f * (Zl.y - Zm.y));
            float2 Dv = make_float2(0.5f * (Zl.x - Zm.x), 0.5f * (Zl.y + Zm.y));
            float2 Fo = make_float2(Dv.y, -Dv.x);
            float s, c; fsincos(-3.14159265358979f * (float)l / 2048.0f, &s, &c);
            float2 TF = make_float2(Fo.x * c - Fo.y * s, Fo.x * s + Fo.y * c);
            op[l] = make_float2(Fe.x + TF.x, Fe.y + TF.y);
            op[2048 - l] = make_float2(Fe.x - TF.x, -(Fe.y - TF.y));
        }
    }
}

// irfft: inverse = conj(forward(conj(Z))). Pack stores conj; GELU reads conj.
// B-planes scaled 1/ISCALE (fp16 range guard); GELU scale = ISCALE/2048.
__global__ __launch_bounds__(256, 3) void irfft_gelu_k(const float2* __restrict__ Uhat,
                                                       float* __restrict__ out,
                                                       const float2* __restrict__ tw,
                                                       const _Float16* __restrict__ F128) {
    __shared__ __align__(16) float2 zx[2 * XROW];
    __shared__ __align__(16) _Float16 Bpl[2 * PLSZ];
    const int tid = threadIdx.x;
    const int row0 = 2 * blockIdx.x;
    #pragma unroll
    for (int r = 0; r < 2; ++r) {
        const float2* wp = Uhat + (size_t)(row0 + r) * LF;
        float2* zr = zx + r * ZROW;
        for (int l = tid; l < 1025; l += 256) {
            float2 Ul = wp[l];
            float2 Um = wp[2048 - l];
            float2 Fe = make_float2(0.5f * (Ul.x + Um.x), 0.5f * (Ul.y - Um.y));
            float2 Dv = make_float2(0.5f * (Ul.x - Um.x), 0.5f * (Ul.y + Um.y));
            float s, c; fsincos(3.14159265358979f * (float)l / 2048.0f, &s, &c);
            float2 Fo = make_float2(Dv.x * c - Dv.y * s, Dv.x * s + Dv.y * c);
            zr[ZIDX(l)] = make_float2(Fe.x - Fo.y, -(Fe.y + Fo.x));        // conj(Fe + i Fo)
            if (l >= 1 && l <= 1023)
                zr[ZIDX(2048 - l)] = make_float2(Fe.x + Fo.y, Fe.y - Fo.x); // conj of mirror
        }
    }
    __syncthreads();
    fourstep2048(zx, Bpl, F128, tw, tid, 1.0f / ISCALE);
    const float SC = ISCALE / 2048.0f;
    #pragma unroll
    for (int r = 0; r < 2; ++r) {
        float4* op4 = (float4*)(out + (size_t)(row0 + r) * Ln);
        const float2* X = zx + r * XROW;
        #pragma unroll
        for (int rr = 0; rr < 4; ++rr) {
            int i = tid + (rr << 8);            // float4 index, 0..1023
            int n = 2 * i;
            float2 z0 = X[SKEW(n)];
            float2 z1 = X[SKEW(n + 1)];
            float y0 = z0.x * SC, y1 = -z0.y * SC;
            float y2 = z1.x * SC, y3 = -z1.y * SC;
            op4[i] = make_float4(
                0.5f * y0 * (1.0f + erff(y0 * 0.70710678118655f)),
                0.5f * y1 * (1.0f + erff(y1 * 0.70710678118655f)),
                0.5f * y2 * (1.0f + erff(y2 * 0.70710678118655f)),
                0.5f * y3 * (1.0f + erff(y3 * 0.70710678118655f)));
        }
    }
}

// ---------------------------------------------------------------------------
// mixmm: byte-identical to r7-r10 (~28 us).
// ---------------------------------------------------------------------------
__global__ __launch_bounds__(256, 4) void mixmm_k(float2* __restrict__ Uhat,
                                                  const _Float16* __restrict__ W1,
                                                  const _Float16* __restrict__ W2,
                                                  const _Float16* __restrict__ W3,
                                                  const float* __restrict__ Lam) {
    __shared__ __align__(16) _Float16 Up[2 * PLSZ];
    __shared__ __align__(16) _Float16 Tp[2 * PLSZ];

    const int tid = threadIdx.x;
    const int b = blockIdx.x / NTILES;
    const int tile = blockIdx.x % NTILES;
    const int l0 = tile * NT;
    const int ncols = (LF - l0) < NT ? (LF - l0) : NT;

    {
        int n = tid & 31, kc = tid >> 5;
        float2 v[16];
        #pragma unroll
        for (int j = 0; j < 16; ++j) {
            int h = kc * 16 + j;
            v[j] = (n < ncols) ? Uhat[(size_t)(b * 128 + h) * LF + l0 + n]
                               : make_float2(0.f, 0.f);
        }
        #pragma unroll
        for (int jc = 0; jc < 2; ++jc) {
            f16x8 fr, fi;
            #pragma unroll
            for (int j = 0; j < 8; ++j) {
                fr[j] = (_Float16)v[jc * 8 + j].x;
                fi[j] = (_Float16)v[jc * 8 + j].y;
            }
            int ksw = (kc * 16 + jc * 8) ^ ((n & 7) << 3);
            *(f16x8*)(Up + 0 * PLSZ + n * 128 + ksw) = fr;
            *(f16x8*)(Up + 1 * PLSZ + n * 128 + ksw) = fi;
        }
    }
    __syncthreads();

    const int lane = tid & 63;
    const int w = tid >> 6;
    const int m15 = lane & 15;
    const int quad = lane >> 4;

    f32x4 accR[2][2], accM[2][2], accI[2][2];
    #pragma unroll
    for (int s = 0; s < 2; ++s)
        #pragma unroll
        for (int t = 0; t < 2; ++t) {
            accR[s][t] = (f32x4)0.f; accM[s][t] = (f32x4)0.f; accI[s][t] = (f32x4)0.f;
        }

    #pragma unroll
    for (int kb = 0; kb < 4; ++kb) {
        int k = kb * 32 + quad * 8;
        f16x8 wr[2], wi[2];
        #pragma unroll
        for (int s = 0; s < 2; ++s) {
            int m = w * 32 + s * 16 + m15;
            wr[s] = aread(W1, 0, m, k);
            wi[s] = aread(W1, 1, m, k);
        }
        f16x8 br[2], bi[2];
        #pragma unroll
        for (int t = 0; t < 2; ++t) {
            br[t] = read_frag(Up + 0 * PLSZ, t * 16 + m15, k);
            bi[t] = read_frag(Up + 1 * PLSZ, t * 16 + m15, k);
        }
        #pragma unroll
        for (int s = 0; s < 2; ++s)
            #pragma unroll
            for (int t = 0; t < 2; ++t) {
                accR[s][t] = mfma16h(wr[s], br[t], accR[s][t]);
                accM[s][t] = mfma16h(wi[s], bi[t], accM[s][t]);
                accI[s][t] = mfma16h(wr[s], bi[t], accI[s][t]);
                accI[s][t] = mfma16h(wi[s], br[t], accI[s][t]);
            }
    }

    #pragma unroll
    for (int s = 0; s < 2; ++s) {
        #pragma unroll
        for (int reg = 0; reg < 4; ++reg) {
            int p = w * 32 + s * 16 + quad * 4 + reg;
            float2 lamv = ((const float2*)Lam)[p];
            float dr = -lamv.x;
            #pragma unroll
            for (int t = 0; t < 2; ++t) {
                int n = t * 16 + m15;
                int l = l0 + n;
                float di = 3.14159265358979f * (float)l / 2048.0f - lamv.y;
                float inv = (1.0f / TSCALE) / (dr * dr + di * di);
                float xr = accR[s][t][reg] - accM[s][t][reg];
                float xi = accI[s][t][reg];
                float tr = (xr * dr + xi * di) * inv;
                float ti = (xi * dr - xr * di) * inv;
                int off = n * 128 + (p ^ ((n & 7) << 3));
                Tp[0 * PLSZ + off] = (_Float16)tr;
                Tp[1 * PLSZ + off] = (_Float16)ti;
            }
        }
    }
    __syncthreads();

    #pragma unroll
    for (int s = 0; s < 2; ++s)
        #pragma unroll
        for (int t = 0; t < 2; ++t) {
            accR[s][t] = (f32x4)0.f; accM[s][t] = (f32x4)0.f; accI[s][t] = (f32x4)0.f;
        }

    #pragma unroll
    for (int kb = 0; kb < 4; ++kb) {
        int k = kb * 32 + quad * 8;
        {
            f16x8 wr[2], wi[2];
            #pragma unroll
            for (int s = 0; s < 2; ++s) {
                int m = w * 32 + s * 16 + m15;
                wr[s] = aread(W2, 0, m, k);
                wi[s] = aread(W2, 1, m, k);
            }
            f16x8 br[2], bi[2];
            #pragma unroll
            for (int t = 0; t < 2; ++t) {
                br[t] = read_frag(Tp + 0 * PLSZ, t * 16 + m15, k);
                bi[t] = read_frag(Tp + 1 * PLSZ, t * 16 + m15, k);
            }
            #pragma unroll
            for (int s = 0; s < 2; ++s)
                #pragma unroll
                for (int t = 0; t < 2; ++t) {
                    accR[s][t] = mfma16h(wr[s], br[t], accR[s][t]);
                    accM[s][t] = mfma16h(wi[s], bi[t], accM[s][t]);
                    accI[s][t] = mfma16h(wr[s], bi[t], accI[s][t]);
                    accI[s][t] = mfma16h(wi[s], br[t], accI[s][t]);
                }
        }
        {
            f16x8 wr[2], wi[2];
            #pragma unroll
            for (int s = 0; s < 2; ++s) {
                int m = w * 32 + s * 16 + m15;
                wr[s] = aread(W3, 0, m, k);
                wi[s] = aread(W3, 1, m, k);
            }
            f16x8 br[2], bi[2];
            #pragma unroll
            for (int t = 0; t < 2; ++t) {
                br[t] = read_frag(Up + 0 * PLSZ, t * 16 + m15, k);
                bi[t] = read_frag(Up + 1 * PLSZ, t * 16 + m15, k);
            }
            #pragma unroll
            for (int s = 0; s < 2; ++s)
                #pragma unroll
                for (int t = 0; t < 2; ++t) {
                    accR[s][t] = mfma16h(wr[s], br[t], accR[s][t]);
                    accM[s][t] = mfma16h(wi[s], bi[t], accM[s][t]);
                    accI[s][t] = mfma16h(wr[s], bi[t], accI[s][t]);
                    accI[s][t] = mfma16h(wi[s], br[t], accI[s][t]);
                }
        }
    }

    #pragma unroll
    for (int s = 0; s < 2; ++s) {
        #pragma unroll
        for (int t = 0; t < 2; ++t) {
            int n = t * 16 + m15;
            if (n < ncols) {
                #pragma unroll
                for (int reg = 0; reg < 4; ++reg) {
                    int m = w * 32 + s * 16 + quad * 4 + reg;
                    Uhat[(size_t)(b * 128 + m) * LF + l0 + n] =
                        make_float2(accR[s][t][reg] - accM[s][t][reg], accI[s][t][reg]);
                }
            }
        }
    }
}

// ---------------------------------------------------------------------------
extern "C" void kernel_launch(void* const* d_in, const int* in_sizes, int n_in,
                              void* d_out, int out_size, void* d_ws, size_t ws_size,
                              hipStream_t stream) {
    const float* u    = (const float*)d_in[0];   // (B,H,L)
    const float* C_ri = (const float*)d_in[1];   // (H,P,2)
    const float* D_ri = (const float*)d_in[2];   // (H,H,2)
    const float* B_ri = (const float*)d_in[3];   // (P,H,2)
    const float* Lam  = (const float*)d_in[4];   // (P,2)
    float* out = (float*)d_out;

    float2* Uhat = (float2*)d_ws;                          // 1024*2049 float2 = 16 MiB
    _Float16* W1 = (_Float16*)(Uhat + (size_t)NROWS * LF);
    _Float16* W2 = W1 + 2 * WPLSZ;
    _Float16* W3 = W2 + 2 * WPLSZ;
    float2* tw = (float2*)(W3 + 2 * WPLSZ);                // 2048 float2 = 16 KB
    _Float16* F128 = (_Float16*)(tw + 2048);               // 2 planes x 32 KB

    prep_all_k<<<160, 256, 0, stream>>>(B_ri, C_ri, D_ri, W1, W2, W3, tw, F128);
    rfft_rows_k<<<NROWS / 2, 256, 0, stream>>>(u, Uhat, tw, F128);
    mixmm_k<<<Bn * NTILES, 256, 0, stream>>>(Uhat, W1, W2, W3, Lam);
    irfft_gelu_k<<<NROWS / 2, 256, 0, stream>>>(Uhat, out, tw, F128);
}